// Round 17
// baseline (52.674 us; speedup 1.0000x reference)
//
#include <hip/hip_runtime.h>

#define Bn   4
#define Nn   1024
#define Mn   100
#define NB   25
#define FEAT 50
#define PIc  3.1415926f
#define RSTEP (5.5f / 24.0f)

#define ATB  16                         // atoms per fused block
#define NATOMS (Bn * Nn)
#define NGPB  65                        // max groups per batch
#define OBATCH (NGPB * ATB)             // 1040 -> pad to 1072 not needed; use 1040
#define MF_BLOCKS (Bn * NGPB)           // 260
#define TYW  122880                     // ushorts per type in wsu
#define PREP_BLKS 341
#define PSTRIDE ((Nn + 1) * 3)          // 3075

typedef __attribute__((ext_vector_type(8))) short bf16x8;
typedef __attribute__((ext_vector_type(4))) float f32x4;

union U16x8 { unsigned short u[8]; bf16x8 v; uint4 q; };

__device__ __forceinline__ unsigned short f2bh(float x) {
    union { float f; unsigned u; } v; v.f = x;
    unsigned r = v.u + 0x7fffu + ((v.u >> 16) & 1u);
    return (unsigned short)(r >> 16);
}
__device__ __forceinline__ float bh2f(unsigned short h) {
    union { unsigned u; float f; } v; v.u = ((unsigned)h) << 16; return v.f;
}
__device__ __forceinline__ float fast_tanh(float x) {
    float ax = fabsf(x);
    float t  = __expf(-2.0f * ax);
    float r  = (1.0f - t) * __builtin_amdgcn_rcpf(1.0f + t);
    return copysignf(r, x);
}

// wsu layout per type (ushort offsets):
// 0      WT0h [128j][64k]   8192   (fwd L0 hi)     8192 WT0l
// 16384  WT1h [128j][128k] 16384   32768 WT1l
// 49152  WT2h             16384    65536 WT2l
// 81920  WRM2 [128i][128j] 16384   (bwd hi only)
// 98304  WRM1             16384
// 114688 WRM0 [64f][128j]  8192

// ------- stage1: weight repack + per-batch sort + Etot zero + feat --------
__global__ __launch_bounds__(256) void stage1_kernel(
    const int* __restrict__ itype, const int* __restrict__ nlist,
    const float* __restrict__ dR,
    const float* __restrict__ W0, const float* __restrict__ W1,
    const float* __restrict__ W2,
    int* __restrict__ order, unsigned short* __restrict__ wsu,
    float* __restrict__ featp, float* __restrict__ Etot)
{
    const int blk = blockIdx.x;
    const int t = threadIdx.x;

    __shared__ float tile[64][65];
    __shared__ int scan[256];
    __shared__ float4 rc4[50];
    __shared__ float fpartial[64];

    if (blk < 20) {
        int ty = blk / 10, m = blk - ty * 10;
        int mat, jt, kt;
        if (m < 2)      { mat = 0; jt = m;            kt = 0; }
        else if (m < 6) { mat = 1; jt = (m - 2) >> 1; kt = (m - 2) & 1; }
        else            { mat = 2; jt = (m - 6) >> 1; kt = (m - 6) & 1; }
        const float* src = (mat == 0) ? W0 + ty * 5000
                          : (mat == 1) ? W1 + ty * 10000 : W2 + ty * 10000;
        const int Krows = (mat == 0) ? 50 : 100;
        const int Ck    = (mat == 0) ? 64 : 128;
        const int dH = ty * TYW + ((mat == 0) ? 0 : (mat == 1) ? 16384 : 49152);
        const int dL = dH + ((mat == 0) ? 8192 : 16384);
        const int j0 = jt * 64, k0 = kt * 64;
        const int rr0 = t >> 6, l = t & 63;
        #pragma unroll
        for (int i = 0; i < 16; ++i) {
            int rr = rr0 + 4 * i;
            int k = k0 + rr, j = j0 + l;
            tile[rr][l] = (k < Krows && j < 100) ? src[k * 100 + j] : 0.0f;
        }
        __syncthreads();
        #pragma unroll
        for (int i = 0; i < 16; ++i) {
            int jj = rr0 + 4 * i;
            float v = tile[l][jj];
            unsigned short h = f2bh(v);
            wsu[dH + (j0 + jj) * Ck + k0 + l] = h;
            wsu[dL + (j0 + jj) * Ck + k0 + l] = f2bh(v - bh2f(h));
        }
        return;
    }
    if (blk < 340) {
        int e = (blk - 20) * 256 + t;
        int ty = e / 40960;
        int r  = e - ty * 40960;
        float v = 0.0f; int dst;
        if (r < 16384) {
            int i = r >> 7, j = r & 127;
            if (i < 100 && j < 100) v = W2[ty * 10000 + i * 100 + j];
            dst = ty * TYW + 81920 + r;
        } else if (r < 32768) {
            int r2 = r - 16384; int i = r2 >> 7, j = r2 & 127;
            if (i < 100 && j < 100) v = W1[ty * 10000 + i * 100 + j];
            dst = ty * TYW + 98304 + r2;
        } else {
            int r2 = r - 32768; int f = r2 >> 7, j = r2 & 127;
            if (f < 50 && j < 100) v = W0[ty * 5000 + f * 100 + j];
            dst = ty * TYW + 114688 + r2;
        }
        wsu[dst] = f2bh(v);
        return;
    }
    if (blk == 340) {
        // per-batch type partition: order[b*OBATCH + ...] holds LOCAL ids
        for (int i = t; i < Bn * OBATCH; i += 256) order[i] = -1;
        __syncthreads();
        for (int b = 0; b < Bn; ++b) {
            int tyv[4]; int c0 = 0;
            #pragma unroll
            for (int k = 0; k < 4; ++k) {
                int tt = (itype[b * Nn + t * 4 + k] == 8) ? 1 : 0;
                tyv[k] = tt; c0 += 1 - tt;
            }
            scan[t] = c0;
            __syncthreads();
            for (int off = 1; off < 256; off <<= 1) {
                int v = scan[t];
                int add = (t >= off) ? scan[t - off] : 0;
                __syncthreads();
                scan[t] = v + add;
                __syncthreads();
            }
            int total0 = scan[255];
            int ex0 = scan[t] - c0;
            int ex1 = 4 * t - ex0;
            int pad0 = (total0 + (ATB - 1)) & ~(ATB - 1);
            int p0 = ex0, p1 = pad0 + ex1;
            #pragma unroll
            for (int k = 0; k < 4; ++k) {
                int n = t * 4 + k;
                if (tyv[k] == 0) order[b * OBATCH + p0++] = n;
                else             order[b * OBATCH + p1++] = n;
            }
            __syncthreads();
        }
        if (t < Bn) Etot[t] = 0.0f;
        return;
    }

    // -------- feat role: atom = blk - PREP_BLKS --------
    const int atom = blk - PREP_BLKS;
    const int b = atom >> 10;

    if (t < Mn) {
        float4 qv = ((const float4*)dR)[(size_t)atom * Mn + t];
        float r = qv.x;
        int v = nlist[(size_t)atom * Mn + t];
        float cws = 0.0f;
        if (v > 0 && r > 0.0f && r < 6.0f) {
            float cw = 0.5f * __cosf(PIc * r) + 0.5f;
            cws = (itype[b * Nn + (v - 1)] == 8) ? -cw : cw;
        }
        ((float2*)rc4)[t] = make_float2(r, cws);
    }
    __syncthreads();

    float acc = 0.0f;
    if (t < 128) {
        const int w = t >> 6, l = t & 63;
        const int tt = l / NB;
        const float rk = 0.5f + (l - tt * NB) * RSTEP;
        #pragma unroll
        for (int i = 0; i < 25; ++i) {
            float4 pr = rc4[w * 25 + i];
            float d0 = pr.x - rk, d1 = pr.z - rk;
            float c0 = tt ? fmaxf(-pr.y, 0.0f) : fmaxf(pr.y, 0.0f);
            float c1 = tt ? fmaxf(-pr.w, 0.0f) : fmaxf(pr.w, 0.0f);
            acc += __expf(-d0 * d0) * c0 + __expf(-d1 * d1) * c1;
        }
        if (w == 1) fpartial[l] = acc;
    }
    __syncthreads();
    if (t < 64)
        featp[(size_t)atom * 64 + t] = (t < FEAT) ? (acc + fpartial[t]) : 0.0f;
}

// --------------------------- mlpforce (fused) ------------------------------
// 512 thr = 8 waves, 16 batch-pure type-pure atoms. MLP fwd+bwd via MFMA
// (dE stays in LDS), then force pair-loop for the SAME atoms; per-block
// batch-wide LDS accumulator -> partial. Ei + Etot also emitted here.
#define ISSUE(RH, RL, OFFU, OFFL, RW, NKT, HASLO, COND)                       \
    if (COND) {                                                               \
        int jj_ = c + 16 * w;                                                 \
        _Pragma("unroll")                                                     \
        for (int kt = 0; kt < (NKT); ++kt) {                                  \
            int boff_ = jj_ * (RW) + kt * 32 + q * 8;                         \
            RH[kt] = *(const bf16x8*)(wb + (OFFU) + boff_);                   \
            if (HASLO) RL[kt] = *(const bf16x8*)(wb + (OFFL) + boff_);        \
        }                                                                     \
    }

#define GEMM_R(ABUF, RH, RL, NKT, HASLO)                                      \
    {                                                                         \
        acc = (f32x4){0,0,0,0}; accl = (f32x4){0,0,0,0};                      \
        _Pragma("unroll")                                                     \
        for (int kt = 0; kt < (NKT); ++kt) {                                  \
            int gk = kt * 4 + q;                                              \
            bf16x8 af = *(const bf16x8*)&aA[ABUF][(c << 7) | ((gk ^ (c & 7)) << 3)]; \
            acc = __builtin_amdgcn_mfma_f32_16x16x32_bf16(af, RH[kt], acc, 0, 0, 0); \
            if (HASLO) accl = __builtin_amdgcn_mfma_f32_16x16x32_bf16(af, RL[kt], accl, 0, 0, 0); \
        }                                                                     \
    }

#define WRACT(BUF, J, A, X)                                                   \
    aA[BUF][((A) << 7) | ((((J) >> 3) ^ ((A) & 7)) << 3) | ((J) & 7)] = f2bh(X)

__global__ __launch_bounds__(512) void mlpforce_kernel(
    const float* __restrict__ featp, const int* __restrict__ itype,
    const int* __restrict__ nlist, const float* __restrict__ dR,
    const int* __restrict__ order, const unsigned short* __restrict__ wsu,
    const float* __restrict__ B0, const float* __restrict__ B1,
    const float* __restrict__ B2, const float* __restrict__ W3,
    const float* __restrict__ B3,
    float* __restrict__ Ei, float* __restrict__ Etot,
    float* __restrict__ partial)
{
    const int t = threadIdx.x;
    const int w = t >> 6;
    const int lane = t & 63;
    const int c = lane & 15, q = lane >> 4;
    const int b = blockIdx.x / NGPB;
    const int grp = blockIdx.x - b * NGPB;

    __shared__ unsigned short aA[2][2048];
    __shared__ float fshf[16][52];
    __shared__ float dx1s[16][112];
    __shared__ float biasS[4][128];
    __shared__ float eip[8][16];
    __shared__ float eivals[16];
    __shared__ float deLDS[16][52];
    __shared__ float facc[PSTRIDE];
    __shared__ int aid[16];

    for (int idx = t; idx < PSTRIDE; idx += 512) facc[idx] = 0.0f;
    if (t < 16) aid[t] = order[b * OBATCH + grp * ATB + t];
    __syncthreads();

    int first = -1;
    #pragma unroll
    for (int a = 0; a < ATB; ++a) { int v = aid[a]; if (first < 0 && v >= 0) first = v; }

    if (first >= 0) {     // block-uniform branch; barriers inside are safe
        const int ty = (itype[b * Nn + first] == 8) ? 1 : 0;
        const unsigned short* wb = wsu + (size_t)ty * TYW;

        bf16x8 bh0[4], bl0[4], bh1[4], bl1[4];
        f32x4 acc, accl;
        float xr[4], h0r[4], h1r[4], h2r[4], dxr[4];

        ISSUE(bh0, bl0, 0, 8192, 64, 2, 1, true);
        if (t < 128) {
            const int srow = t >> 3, sg = t & 7;
            int v = aid[srow];
            float4 fa = {0,0,0,0}, fb = {0,0,0,0};
            if (v >= 0) {
                const float4* fp = (const float4*)(featp + ((size_t)(b * Nn + v)) * 64 + sg * 8);
                fa = fp[0]; fb = fp[1];
            }
            U16x8 pk;
            pk.u[0]=f2bh(fa.x); pk.u[1]=f2bh(fa.y); pk.u[2]=f2bh(fa.z); pk.u[3]=f2bh(fa.w);
            pk.u[4]=f2bh(fb.x); pk.u[5]=f2bh(fb.y); pk.u[6]=f2bh(fb.z); pk.u[7]=f2bh(fb.w);
            *(uint4*)&aA[0][(srow << 7) | ((sg ^ (srow & 7)) << 3)] = pk.q;
            int cbase = sg * 8;
            if (cbase < 52) {
                float vals[8] = {fa.x,fa.y,fa.z,fa.w,fb.x,fb.y,fb.z,fb.w};
                #pragma unroll
                for (int j7 = 0; j7 < 8; ++j7)
                    if (cbase + j7 < 52) fshf[srow][cbase + j7] = vals[j7];
            }
        }
        {
            int row = t >> 7, col = t & 127;
            const float* s = (row == 0) ? B0 : (row == 1) ? B1 : (row == 2) ? B2 : W3;
            biasS[row][col] = (col < 100) ? s[ty * 100 + col] : 0.0f;
        }
        __syncthreads();

        // P0
        ISSUE(bh1, bl1, 16384, 32768, 128, 4, 1, true);
        GEMM_R(0, bh0, bl0, 2, 1);
        {
            int j = c + 16 * w;
            float bj = biasS[0][j];
            #pragma unroll
            for (int r = 0; r < 4; ++r) {
                int a = q * 4 + r;
                float z = acc[r] + accl[r] + bj;
                float h = 0.f, x = 0.f;
                if (j < 100) { h = fast_tanh(z); x = h + fshf[a][(j < 50) ? j : j - 50]; }
                h0r[r] = h; xr[r] = x;
                WRACT(1, j, a, x);
            }
        }
        __syncthreads();

        // P1
        ISSUE(bh0, bl0, 49152, 65536, 128, 4, 1, true);
        GEMM_R(1, bh1, bl1, 4, 1);
        {
            int j = c + 16 * w;
            float bj = biasS[1][j];
            #pragma unroll
            for (int r = 0; r < 4; ++r) {
                int a = q * 4 + r;
                float z = acc[r] + accl[r] + bj;
                float h = (j < 100) ? fast_tanh(z) : 0.f;
                float x = (j < 100) ? (h + xr[r]) : 0.f;
                h1r[r] = h; xr[r] = x;
                WRACT(0, j, a, x);
            }
        }
        __syncthreads();

        // P2
        ISSUE(bh1, bl1, 81920, 0, 128, 4, 0, true);
        GEMM_R(0, bh0, bl0, 4, 1);
        {
            int j = c + 16 * w;
            float bj = biasS[2][j];
            float wv = biasS[3][j];
            float p4v[4];
            #pragma unroll
            for (int r = 0; r < 4; ++r) {
                float z = acc[r] + accl[r] + bj;
                float h = (j < 100) ? fast_tanh(z) : 0.f;
                h2r[r] = h;
                xr[r] = (j < 100) ? (h + xr[r]) : 0.f;
                p4v[r] = xr[r] * wv;
            }
            #pragma unroll
            for (int off = 1; off < 16; off <<= 1) {
                #pragma unroll
                for (int r = 0; r < 4; ++r) p4v[r] += __shfl_xor(p4v[r], off);
            }
            if (c == 0) {
                #pragma unroll
                for (int r = 0; r < 4; ++r) eip[w][q * 4 + r] = p4v[r];
            }
            #pragma unroll
            for (int r = 0; r < 4; ++r) {
                int a = q * 4 + r;
                float d = wv * (1.0f - h2r[r] * h2r[r]);
                WRACT(1, j, a, d);
            }
        }
        __syncthreads();
        if (t < 16) {
            int v = aid[t];
            float e = 0.0f;
            if (v >= 0) {
                e = B3[ty];
                #pragma unroll
                for (int ww = 0; ww < 8; ++ww) e += eip[ww][t];
                Ei[b * Nn + v] = e;
            }
            eivals[t] = e;
        }

        // P3
        ISSUE(bh0, bl0, 98304, 0, 128, 4, 0, true);
        GEMM_R(1, bh1, bl1, 4, 0);
        {
            int i = c + 16 * w;
            float w3i = biasS[3][i];
            #pragma unroll
            for (int r = 0; r < 4; ++r) {
                int a = q * 4 + r;
                float dx2 = acc[r] + w3i;
                dxr[r] = dx2;
                float d = dx2 * (1.0f - h1r[r] * h1r[r]);
                WRACT(0, i, a, d);
            }
        }
        __syncthreads();

        // P4
        ISSUE(bh1, bl1, 114688, 0, 128, 4, 0, (w < 4));
        GEMM_R(0, bh0, bl0, 4, 0);
        {
            int i = c + 16 * w;
            #pragma unroll
            for (int r = 0; r < 4; ++r) {
                int a = q * 4 + r;
                float dx1 = dxr[r] + acc[r];
                if (i < 112) dx1s[a][i] = dx1;
                float d = dx1 * (1.0f - h0r[r] * h0r[r]);
                WRACT(1, i, a, d);
            }
        }
        __syncthreads();

        // P5: dE -> LDS only
        if (w < 4) {
            GEMM_R(1, bh1, bl1, 4, 0);
            int f = c + 16 * w;
            if (f < 50) {
                #pragma unroll
                for (int r = 0; r < 4; ++r) {
                    int a = q * 4 + r;
                    deLDS[a][f] = acc[r] + dx1s[a][f] + dx1s[a][f + 50];
                }
            }
        }
        __syncthreads();

        // ---- fused force: wave w handles atoms 2w, 2w+1 ----
        if (t == 0) {
            float s = 0.0f;
            #pragma unroll
            for (int i = 0; i < 16; ++i) s += eivals[i];
            atomicAdd(&Etot[b], s);
        }
        #pragma unroll
        for (int ai = 0; ai < 2; ++ai) {
            const int a = w * 2 + ai;
            const int n = aid[a];
            if (n >= 0) {                           // wave-uniform
                const size_t pairbase = (size_t)(b * Nn + n) * Mn;
                const int m1 = lane + 64;
                float4 qv0 = ((const float4*)dR)[pairbase + lane];
                int    v0  = nlist[pairbase + lane];
                float4 qv1 = make_float4(0.f, 0.f, 0.f, 0.f);
                int    v1  = 0;
                if (m1 < Mn) {
                    qv1 = ((const float4*)dR)[pairbase + m1];
                    v1  = nlist[pairbase + m1];
                }
                float cfx = 0.f, cfy = 0.f, cfz = 0.f;
                #pragma unroll
                for (int mi = 0; mi < 2; ++mi) {
                    float4 qv = mi ? qv1 : qv0;
                    int v = mi ? v1 : v0;
                    if (v > 0) {
                        float r = qv.x;
                        if (r > 0.0f && r < 6.0f) {
                            int tt = (itype[b * Nn + v - 1] == 8) ? 1 : 0;
                            float cw  = 0.5f * __cosf(PIc * r) + 0.5f;
                            float dcw = -0.5f * PIc * __sinf(PIc * r);
                            float s = 0.0f;
                            const float* de = &deLDS[a][tt * NB];
                            #pragma unroll
                            for (int k = 0; k < NB; ++k) {
                                float d = r - (0.5f + k * RSTEP);
                                float e = __expf(-d * d);
                                s += de[k] * e * __builtin_fmaf(-2.0f * cw, d, dcw);
                            }
                            float inv = 1.0f / r;
                            float fx = s * qv.y * inv, fy = s * qv.z * inv, fz = s * qv.w * inv;
                            atomicAdd(&facc[v * 3 + 0], fx);
                            atomicAdd(&facc[v * 3 + 1], fy);
                            atomicAdd(&facc[v * 3 + 2], fz);
                            cfx += fx; cfy += fy; cfz += fz;
                        }
                    }
                }
                #pragma unroll
                for (int off = 32; off > 0; off >>= 1) {
                    cfx += __shfl_xor(cfx, off);
                    cfy += __shfl_xor(cfy, off);
                    cfz += __shfl_xor(cfz, off);
                }
                if (lane == 0) {
                    atomicAdd(&facc[(n + 1) * 3 + 0], -cfx);
                    atomicAdd(&facc[(n + 1) * 3 + 1], -cfy);
                    atomicAdd(&facc[(n + 1) * 3 + 2], -cfz);
                }
            }
        }
    }
    __syncthreads();

    float* pout = partial + (size_t)blockIdx.x * PSTRIDE;
    for (int idx = t; idx < PSTRIDE; idx += 512) pout[idx] = facc[idx];
}

// -------------------------------------------------------------- freduce ---
__global__ __launch_bounds__(256) void freduce_kernel(
    const float* __restrict__ partial, float* __restrict__ Force)
{
    int idx = blockIdx.x * 256 + threadIdx.x;
    if (idx >= Bn * Nn * 3) return;
    int b = idx / (Nn * 3);
    int r = idx - b * (Nn * 3);
    int i = r / 3, ch = r - i * 3;
    float s = 0.0f;
    for (int g = 0; g < NGPB; ++g)
        s += partial[((size_t)(b * NGPB + g)) * PSTRIDE + (size_t)(i + 1) * 3 + ch];
    Force[idx] = s;
}

// -------------------------------------------------------------- launch ----
extern "C" void kernel_launch(void* const* d_in, const int* in_sizes, int n_in,
                              void* d_out, int out_size, void* d_ws, size_t ws_size,
                              hipStream_t stream)
{
    const int*   itype = (const int*)d_in[0];
    const int*   nlist = (const int*)d_in[1];
    const float* dR    = (const float*)d_in[2];
    const float* W0 = (const float*)d_in[3];  const float* B0 = (const float*)d_in[4];
    const float* W1 = (const float*)d_in[5];  const float* B1 = (const float*)d_in[6];
    const float* W2 = (const float*)d_in[7];  const float* B2 = (const float*)d_in[8];
    const float* W3 = (const float*)d_in[9];  const float* B3 = (const float*)d_in[10];

    float* out   = (float*)d_out;
    float* Etot  = out;                    // [B,1]
    float* Ei    = out + Bn;               // [B,N,1]
    float* Force = out + Bn + Bn * Nn;     // [B,N,3]

    float* featp   = (float*)d_ws;                               // NATOMS*64 f32
    float* partial = featp + (size_t)NATOMS * 64;                // 260*3075 f32
    int*   order   = (int*)(partial + (size_t)MF_BLOCKS * PSTRIDE);
    unsigned short* wsu = (unsigned short*)(order + Bn * OBATCH);

    stage1_kernel  <<<PREP_BLKS + NATOMS, 256, 0, stream>>>(itype, nlist, dR,
                                                            W0, W1, W2,
                                                            order, wsu, featp, Etot);
    mlpforce_kernel<<<MF_BLOCKS, 512, 0, stream>>>(featp, itype, nlist, dR,
                                                   order, wsu,
                                                   B0, B1, B2, W3, B3,
                                                   Ei, Etot, partial);
    freduce_kernel <<<(Bn * Nn * 3 + 255) / 256, 256, 0, stream>>>(partial, Force);
}

// Round 18
// 49.949 us; speedup vs baseline: 1.0545x; 1.0545x over previous
//
#include <hip/hip_runtime.h>

#define Bn   4
#define Nn   1024
#define Mn   100
#define NB   25
#define FEAT 50
#define PIc  3.1415926f
#define RSTEP (5.5f / 24.0f)

#define ATB  32                         // atoms per fused block (2 MFMA row-tiles)
#define NATOMS (Bn * Nn)
#define NGPB  33                        // max groups per batch (ceil + pad)
#define OBATCH (NGPB * ATB)             // 1056
#define MF_BLOCKS (Bn * NGPB)           // 132  (single CU round)
#define TYW  122880                     // ushorts per type in wsu
#define PREP_BLKS 341
#define PSTRIDE ((Nn + 1) * 3)          // 3075

typedef __attribute__((ext_vector_type(8))) short bf16x8;
typedef __attribute__((ext_vector_type(4))) float f32x4;

union U16x8 { unsigned short u[8]; bf16x8 v; uint4 q; };

__device__ __forceinline__ unsigned short f2bh(float x) {
    union { float f; unsigned u; } v; v.f = x;
    unsigned r = v.u + 0x7fffu + ((v.u >> 16) & 1u);
    return (unsigned short)(r >> 16);
}
__device__ __forceinline__ float bh2f(unsigned short h) {
    union { unsigned u; float f; } v; v.u = ((unsigned)h) << 16; return v.f;
}
__device__ __forceinline__ float fast_tanh(float x) {
    float ax = fabsf(x);
    float t  = __expf(-2.0f * ax);
    float r  = (1.0f - t) * __builtin_amdgcn_rcpf(1.0f + t);
    return copysignf(r, x);
}

// wsu layout per type (ushort offsets):
// 0      WT0h [128j][64k]   8192   (fwd L0 hi)     8192 WT0l
// 16384  WT1h [128j][128k] 16384   32768 WT1l
// 49152  WT2h             16384    65536 WT2l
// 81920  WRM2 [128i][128j] 16384   (bwd hi only)
// 98304  WRM1             16384
// 114688 WRM0 [64f][128j]  8192

// ------- stage1: weight repack + per-batch sort + Etot zero + feat --------
__global__ __launch_bounds__(256) void stage1_kernel(
    const int* __restrict__ itype, const int* __restrict__ nlist,
    const float* __restrict__ dR,
    const float* __restrict__ W0, const float* __restrict__ W1,
    const float* __restrict__ W2,
    int* __restrict__ order, unsigned short* __restrict__ wsu,
    float* __restrict__ featp, float* __restrict__ Etot)
{
    const int blk = blockIdx.x;
    const int t = threadIdx.x;

    __shared__ float tile[64][65];
    __shared__ int scan[256];
    __shared__ float4 rc4[50];
    __shared__ float fpartial[64];

    if (blk < 20) {
        int ty = blk / 10, m = blk - ty * 10;
        int mat, jt, kt;
        if (m < 2)      { mat = 0; jt = m;            kt = 0; }
        else if (m < 6) { mat = 1; jt = (m - 2) >> 1; kt = (m - 2) & 1; }
        else            { mat = 2; jt = (m - 6) >> 1; kt = (m - 6) & 1; }
        const float* src = (mat == 0) ? W0 + ty * 5000
                          : (mat == 1) ? W1 + ty * 10000 : W2 + ty * 10000;
        const int Krows = (mat == 0) ? 50 : 100;
        const int Ck    = (mat == 0) ? 64 : 128;
        const int dH = ty * TYW + ((mat == 0) ? 0 : (mat == 1) ? 16384 : 49152);
        const int dL = dH + ((mat == 0) ? 8192 : 16384);
        const int j0 = jt * 64, k0 = kt * 64;
        const int rr0 = t >> 6, l = t & 63;
        #pragma unroll
        for (int i = 0; i < 16; ++i) {
            int rr = rr0 + 4 * i;
            int k = k0 + rr, j = j0 + l;
            tile[rr][l] = (k < Krows && j < 100) ? src[k * 100 + j] : 0.0f;
        }
        __syncthreads();
        #pragma unroll
        for (int i = 0; i < 16; ++i) {
            int jj = rr0 + 4 * i;
            float v = tile[l][jj];
            unsigned short h = f2bh(v);
            wsu[dH + (j0 + jj) * Ck + k0 + l] = h;
            wsu[dL + (j0 + jj) * Ck + k0 + l] = f2bh(v - bh2f(h));
        }
        return;
    }
    if (blk < 340) {
        int e = (blk - 20) * 256 + t;
        int ty = e / 40960;
        int r  = e - ty * 40960;
        float v = 0.0f; int dst;
        if (r < 16384) {
            int i = r >> 7, j = r & 127;
            if (i < 100 && j < 100) v = W2[ty * 10000 + i * 100 + j];
            dst = ty * TYW + 81920 + r;
        } else if (r < 32768) {
            int r2 = r - 16384; int i = r2 >> 7, j = r2 & 127;
            if (i < 100 && j < 100) v = W1[ty * 10000 + i * 100 + j];
            dst = ty * TYW + 98304 + r2;
        } else {
            int r2 = r - 32768; int f = r2 >> 7, j = r2 & 127;
            if (f < 50 && j < 100) v = W0[ty * 5000 + f * 100 + j];
            dst = ty * TYW + 114688 + r2;
        }
        wsu[dst] = f2bh(v);
        return;
    }
    if (blk == 340) {
        // per-batch type partition (LOCAL ids), pad segments to ATB=32
        for (int i = t; i < Bn * OBATCH; i += 256) order[i] = -1;
        __syncthreads();
        for (int b = 0; b < Bn; ++b) {
            int tyv[4]; int c0 = 0;
            #pragma unroll
            for (int k = 0; k < 4; ++k) {
                int tt = (itype[b * Nn + t * 4 + k] == 8) ? 1 : 0;
                tyv[k] = tt; c0 += 1 - tt;
            }
            scan[t] = c0;
            __syncthreads();
            for (int off = 1; off < 256; off <<= 1) {
                int v = scan[t];
                int add = (t >= off) ? scan[t - off] : 0;
                __syncthreads();
                scan[t] = v + add;
                __syncthreads();
            }
            int total0 = scan[255];
            int ex0 = scan[t] - c0;
            int ex1 = 4 * t - ex0;
            int pad0 = (total0 + (ATB - 1)) & ~(ATB - 1);
            int p0 = ex0, p1 = pad0 + ex1;
            #pragma unroll
            for (int k = 0; k < 4; ++k) {
                int n = t * 4 + k;
                if (tyv[k] == 0) order[b * OBATCH + p0++] = n;
                else             order[b * OBATCH + p1++] = n;
            }
            __syncthreads();
        }
        if (t < Bn) Etot[t] = 0.0f;
        return;
    }

    // -------- feat role: atom = blk - PREP_BLKS --------
    const int atom = blk - PREP_BLKS;
    const int b = atom >> 10;

    if (t < Mn) {
        float4 qv = ((const float4*)dR)[(size_t)atom * Mn + t];
        float r = qv.x;
        int v = nlist[(size_t)atom * Mn + t];
        float cws = 0.0f;
        if (v > 0 && r > 0.0f && r < 6.0f) {
            float cw = 0.5f * __cosf(PIc * r) + 0.5f;
            cws = (itype[b * Nn + (v - 1)] == 8) ? -cw : cw;
        }
        ((float2*)rc4)[t] = make_float2(r, cws);
    }
    __syncthreads();

    float acc = 0.0f;
    if (t < 128) {
        const int w = t >> 6, l = t & 63;
        const int tt = l / NB;
        const float rk = 0.5f + (l - tt * NB) * RSTEP;
        #pragma unroll
        for (int i = 0; i < 25; ++i) {
            float4 pr = rc4[w * 25 + i];
            float d0 = pr.x - rk, d1 = pr.z - rk;
            float c0 = tt ? fmaxf(-pr.y, 0.0f) : fmaxf(pr.y, 0.0f);
            float c1 = tt ? fmaxf(-pr.w, 0.0f) : fmaxf(pr.w, 0.0f);
            acc += __expf(-d0 * d0) * c0 + __expf(-d1 * d1) * c1;
        }
        if (w == 1) fpartial[l] = acc;
    }
    __syncthreads();
    if (t < 64)
        featp[(size_t)atom * 64 + t] = (t < FEAT) ? (acc + fpartial[t]) : 0.0f;
}

// --------------------------- mlpforce (fused, ATB=32) ----------------------
// 512 thr = 8 waves, 32 batch-pure type-pure atoms as TWO 16-row MFMA tiles.
// Weight fragments shared across both row tiles (2x reuse, same load count).
#define ISSUE(RH, RL, OFFU, OFFL, RW, NKT, HASLO, COND)                       \
    if (COND) {                                                               \
        int jj_ = c + 16 * w;                                                 \
        _Pragma("unroll")                                                     \
        for (int kt = 0; kt < (NKT); ++kt) {                                  \
            int boff_ = jj_ * (RW) + kt * 32 + q * 8;                         \
            RH[kt] = *(const bf16x8*)(wb + (OFFU) + boff_);                   \
            if (HASLO) RL[kt] = *(const bf16x8*)(wb + (OFFL) + boff_);        \
        }                                                                     \
    }

#define GEMM_R2(ABUF, RH, RL, NKT, HASLO)                                     \
    {                                                                         \
        acc[0] = (f32x4){0,0,0,0}; acc[1] = acc[0];                           \
        accl[0] = acc[0]; accl[1] = acc[0];                                   \
        _Pragma("unroll")                                                     \
        for (int kt = 0; kt < (NKT); ++kt) {                                  \
            int gk = kt * 4 + q;                                              \
            int sw = ((gk ^ (c & 7)) << 3);                                   \
            bf16x8 af0 = *(const bf16x8*)&aA[ABUF][(c << 7) | sw];            \
            bf16x8 af1 = *(const bf16x8*)&aA[ABUF][((c + 16) << 7) | sw];     \
            acc[0] = __builtin_amdgcn_mfma_f32_16x16x32_bf16(af0, RH[kt], acc[0], 0, 0, 0); \
            acc[1] = __builtin_amdgcn_mfma_f32_16x16x32_bf16(af1, RH[kt], acc[1], 0, 0, 0); \
            if (HASLO) {                                                      \
                accl[0] = __builtin_amdgcn_mfma_f32_16x16x32_bf16(af0, RL[kt], accl[0], 0, 0, 0); \
                accl[1] = __builtin_amdgcn_mfma_f32_16x16x32_bf16(af1, RL[kt], accl[1], 0, 0, 0); \
            }                                                                 \
        }                                                                     \
    }

#define WRACT(BUF, J, A, X)                                                   \
    aA[BUF][((A) << 7) | ((((J) >> 3) ^ ((A) & 7)) << 3) | ((J) & 7)] = f2bh(X)

__global__ __launch_bounds__(512) void mlpforce_kernel(
    const float* __restrict__ featp, const int* __restrict__ itype,
    const int* __restrict__ nlist, const float* __restrict__ dR,
    const int* __restrict__ order, const unsigned short* __restrict__ wsu,
    const float* __restrict__ B0, const float* __restrict__ B1,
    const float* __restrict__ B2, const float* __restrict__ W3,
    const float* __restrict__ B3,
    float* __restrict__ Ei, float* __restrict__ Etot,
    float* __restrict__ partial)
{
    const int t = threadIdx.x;
    const int w = t >> 6;
    const int lane = t & 63;
    const int c = lane & 15, q = lane >> 4;
    const int b = blockIdx.x / NGPB;
    const int grp = blockIdx.x - b * NGPB;

    __shared__ unsigned short aA[2][4096];      // 32x128 bf16 x2 (16KB)
    __shared__ float fshf[32][52];
    __shared__ float dx1s[32][112];
    __shared__ float biasS[4][128];
    __shared__ float eip[8][32];
    __shared__ float eivals[32];
    __shared__ float deLDS[32][52];
    __shared__ float facc[PSTRIDE];
    __shared__ int aid[32];

    for (int idx = t; idx < PSTRIDE; idx += 512) facc[idx] = 0.0f;
    if (t < 32) aid[t] = order[b * OBATCH + grp * ATB + t];
    __syncthreads();

    int first = -1;
    #pragma unroll
    for (int a = 0; a < ATB; ++a) { int v = aid[a]; if (first < 0 && v >= 0) first = v; }

    if (first >= 0) {     // block-uniform
        const int ty = (itype[b * Nn + first] == 8) ? 1 : 0;
        const unsigned short* wb = wsu + (size_t)ty * TYW;

        bf16x8 bh0[4], bl0[4], bh1[4], bl1[4];
        f32x4 acc[2], accl[2];
        float xr[2][4], h0r[2][4], h1r[2][4], h2r[2][4], dxr[2][4];

        ISSUE(bh0, bl0, 0, 8192, 64, 2, 1, true);
        if (t < 256) {
            const int srow = t >> 3, sg = t & 7;
            int v = aid[srow];
            float4 fa = {0,0,0,0}, fb = {0,0,0,0};
            if (v >= 0) {
                const float4* fp = (const float4*)(featp + ((size_t)(b * Nn + v)) * 64 + sg * 8);
                fa = fp[0]; fb = fp[1];
            }
            U16x8 pk;
            pk.u[0]=f2bh(fa.x); pk.u[1]=f2bh(fa.y); pk.u[2]=f2bh(fa.z); pk.u[3]=f2bh(fa.w);
            pk.u[4]=f2bh(fb.x); pk.u[5]=f2bh(fb.y); pk.u[6]=f2bh(fb.z); pk.u[7]=f2bh(fb.w);
            *(uint4*)&aA[0][(srow << 7) | ((sg ^ (srow & 7)) << 3)] = pk.q;
            int cbase = sg * 8;
            if (cbase < 52) {
                float vals[8] = {fa.x,fa.y,fa.z,fa.w,fb.x,fb.y,fb.z,fb.w};
                #pragma unroll
                for (int j7 = 0; j7 < 8; ++j7)
                    if (cbase + j7 < 52) fshf[srow][cbase + j7] = vals[j7];
            }
        }
        {
            int row = t >> 7, col = t & 127;
            const float* s = (row == 0) ? B0 : (row == 1) ? B1 : (row == 2) ? B2 : W3;
            biasS[row][col] = (col < 100) ? s[ty * 100 + col] : 0.0f;
        }
        __syncthreads();

        // P0: L0 fwd
        ISSUE(bh1, bl1, 16384, 32768, 128, 4, 1, true);
        GEMM_R2(0, bh0, bl0, 2, 1);
        {
            int j = c + 16 * w;
            float bj = biasS[0][j];
            #pragma unroll
            for (int rt = 0; rt < 2; ++rt) {
                #pragma unroll
                for (int r = 0; r < 4; ++r) {
                    int a = rt * 16 + q * 4 + r;
                    float z = acc[rt][r] + accl[rt][r] + bj;
                    float h = 0.f, x = 0.f;
                    if (j < 100) { h = fast_tanh(z); x = h + fshf[a][(j < 50) ? j : j - 50]; }
                    h0r[rt][r] = h; xr[rt][r] = x;
                    WRACT(1, j, a, x);
                }
            }
        }
        __syncthreads();

        // P1: L1 fwd
        ISSUE(bh0, bl0, 49152, 65536, 128, 4, 1, true);
        GEMM_R2(1, bh1, bl1, 4, 1);
        {
            int j = c + 16 * w;
            float bj = biasS[1][j];
            #pragma unroll
            for (int rt = 0; rt < 2; ++rt) {
                #pragma unroll
                for (int r = 0; r < 4; ++r) {
                    int a = rt * 16 + q * 4 + r;
                    float z = acc[rt][r] + accl[rt][r] + bj;
                    float h = (j < 100) ? fast_tanh(z) : 0.f;
                    float x = (j < 100) ? (h + xr[rt][r]) : 0.f;
                    h1r[rt][r] = h; xr[rt][r] = x;
                    WRACT(0, j, a, x);
                }
            }
        }
        __syncthreads();

        // P2: L2 fwd -> Ei partials, dz2
        ISSUE(bh1, bl1, 81920, 0, 128, 4, 0, true);
        GEMM_R2(0, bh0, bl0, 4, 1);
        {
            int j = c + 16 * w;
            float bj = biasS[2][j];
            float wv = biasS[3][j];
            float p4v[2][4];
            #pragma unroll
            for (int rt = 0; rt < 2; ++rt) {
                #pragma unroll
                for (int r = 0; r < 4; ++r) {
                    float z = acc[rt][r] + accl[rt][r] + bj;
                    float h = (j < 100) ? fast_tanh(z) : 0.f;
                    h2r[rt][r] = h;
                    xr[rt][r] = (j < 100) ? (h + xr[rt][r]) : 0.f;
                    p4v[rt][r] = xr[rt][r] * wv;
                }
            }
            #pragma unroll
            for (int off = 1; off < 16; off <<= 1) {
                #pragma unroll
                for (int rt = 0; rt < 2; ++rt) {
                    #pragma unroll
                    for (int r = 0; r < 4; ++r) p4v[rt][r] += __shfl_xor(p4v[rt][r], off);
                }
            }
            if (c == 0) {
                #pragma unroll
                for (int rt = 0; rt < 2; ++rt) {
                    #pragma unroll
                    for (int r = 0; r < 4; ++r) eip[w][rt * 16 + q * 4 + r] = p4v[rt][r];
                }
            }
            #pragma unroll
            for (int rt = 0; rt < 2; ++rt) {
                #pragma unroll
                for (int r = 0; r < 4; ++r) {
                    int a = rt * 16 + q * 4 + r;
                    float d = wv * (1.0f - h2r[rt][r] * h2r[rt][r]);
                    WRACT(1, j, a, d);
                }
            }
        }
        __syncthreads();
        if (t < 32) {
            int v = aid[t];
            float e = 0.0f;
            if (v >= 0) {
                e = B3[ty];
                #pragma unroll
                for (int ww = 0; ww < 8; ++ww) e += eip[ww][t];
                Ei[b * Nn + v] = e;
            }
            eivals[t] = e;
        }

        // P3: bwd2 -> dz1
        ISSUE(bh0, bl0, 98304, 0, 128, 4, 0, true);
        GEMM_R2(1, bh1, bl1, 4, 0);
        {
            int i = c + 16 * w;
            float w3i = biasS[3][i];
            #pragma unroll
            for (int rt = 0; rt < 2; ++rt) {
                #pragma unroll
                for (int r = 0; r < 4; ++r) {
                    int a = rt * 16 + q * 4 + r;
                    float dx2 = acc[rt][r] + w3i;
                    dxr[rt][r] = dx2;
                    float d = dx2 * (1.0f - h1r[rt][r] * h1r[rt][r]);
                    WRACT(0, i, a, d);
                }
            }
        }
        __syncthreads();

        // P4: bwd1 -> dz0, dx1s
        ISSUE(bh1, bl1, 114688, 0, 128, 4, 0, (w < 4));
        GEMM_R2(0, bh0, bl0, 4, 0);
        {
            int i = c + 16 * w;
            #pragma unroll
            for (int rt = 0; rt < 2; ++rt) {
                #pragma unroll
                for (int r = 0; r < 4; ++r) {
                    int a = rt * 16 + q * 4 + r;
                    float dx1 = dxr[rt][r] + acc[rt][r];
                    if (i < 112) dx1s[a][i] = dx1;
                    float d = dx1 * (1.0f - h0r[rt][r] * h0r[rt][r]);
                    WRACT(1, i, a, d);
                }
            }
        }
        __syncthreads();

        // P5: bwd0 -> dE (LDS only), waves 0-3
        if (w < 4) {
            GEMM_R2(1, bh1, bl1, 4, 0);
            int f = c + 16 * w;
            if (f < 50) {
                #pragma unroll
                for (int rt = 0; rt < 2; ++rt) {
                    #pragma unroll
                    for (int r = 0; r < 4; ++r) {
                        int a = rt * 16 + q * 4 + r;
                        deLDS[a][f] = acc[rt][r] + dx1s[a][f] + dx1s[a][f + 50];
                    }
                }
            }
        }
        __syncthreads();

        // ---- fused force: wave w owns atoms 4w..4w+3 ----
        if (t == 0) {
            float s = 0.0f;
            #pragma unroll
            for (int i = 0; i < 32; ++i) s += eivals[i];
            atomicAdd(&Etot[b], s);
        }
        #pragma unroll
        for (int ai = 0; ai < 4; ++ai) {
            const int a = w * 4 + ai;
            const int n = aid[a];
            if (n >= 0) {                           // wave-uniform
                const size_t pairbase = (size_t)(b * Nn + n) * Mn;
                const int m1 = lane + 64;
                float4 qv0 = ((const float4*)dR)[pairbase + lane];
                int    v0  = nlist[pairbase + lane];
                float4 qv1 = make_float4(0.f, 0.f, 0.f, 0.f);
                int    v1  = 0;
                if (m1 < Mn) {
                    qv1 = ((const float4*)dR)[pairbase + m1];
                    v1  = nlist[pairbase + m1];
                }
                float cfx = 0.f, cfy = 0.f, cfz = 0.f;
                #pragma unroll
                for (int mi = 0; mi < 2; ++mi) {
                    float4 qv = mi ? qv1 : qv0;
                    int v = mi ? v1 : v0;
                    if (v > 0) {
                        float r = qv.x;
                        if (r > 0.0f && r < 6.0f) {
                            int tt = (itype[b * Nn + v - 1] == 8) ? 1 : 0;
                            float cw  = 0.5f * __cosf(PIc * r) + 0.5f;
                            float dcw = -0.5f * PIc * __sinf(PIc * r);
                            float s = 0.0f;
                            const float* de = &deLDS[a][tt * NB];
                            #pragma unroll
                            for (int k = 0; k < NB; ++k) {
                                float d = r - (0.5f + k * RSTEP);
                                float e = __expf(-d * d);
                                s += de[k] * e * __builtin_fmaf(-2.0f * cw, d, dcw);
                            }
                            float inv = 1.0f / r;
                            float fx = s * qv.y * inv, fy = s * qv.z * inv, fz = s * qv.w * inv;
                            atomicAdd(&facc[v * 3 + 0], fx);
                            atomicAdd(&facc[v * 3 + 1], fy);
                            atomicAdd(&facc[v * 3 + 2], fz);
                            cfx += fx; cfy += fy; cfz += fz;
                        }
                    }
                }
                #pragma unroll
                for (int off = 32; off > 0; off >>= 1) {
                    cfx += __shfl_xor(cfx, off);
                    cfy += __shfl_xor(cfy, off);
                    cfz += __shfl_xor(cfz, off);
                }
                if (lane == 0) {
                    atomicAdd(&facc[(n + 1) * 3 + 0], -cfx);
                    atomicAdd(&facc[(n + 1) * 3 + 1], -cfy);
                    atomicAdd(&facc[(n + 1) * 3 + 2], -cfz);
                }
            }
        }
    }
    __syncthreads();

    float* pout = partial + (size_t)blockIdx.x * PSTRIDE;
    for (int idx = t; idx < PSTRIDE; idx += 512) pout[idx] = facc[idx];
}

// -------------------------------------------------------------- freduce ---
__global__ __launch_bounds__(256) void freduce_kernel(
    const float* __restrict__ partial, float* __restrict__ Force)
{
    int idx = blockIdx.x * 256 + threadIdx.x;
    if (idx >= Bn * Nn * 3) return;
    int b = idx / (Nn * 3);
    int r = idx - b * (Nn * 3);
    int i = r / 3, ch = r - i * 3;
    float s = 0.0f;
    #pragma unroll 8
    for (int g = 0; g < NGPB; ++g)
        s += partial[((size_t)(b * NGPB + g)) * PSTRIDE + (size_t)(i + 1) * 3 + ch];
    Force[idx] = s;
}

// -------------------------------------------------------------- launch ----
extern "C" void kernel_launch(void* const* d_in, const int* in_sizes, int n_in,
                              void* d_out, int out_size, void* d_ws, size_t ws_size,
                              hipStream_t stream)
{
    const int*   itype = (const int*)d_in[0];
    const int*   nlist = (const int*)d_in[1];
    const float* dR    = (const float*)d_in[2];
    const float* W0 = (const float*)d_in[3];  const float* B0 = (const float*)d_in[4];
    const float* W1 = (const float*)d_in[5];  const float* B1 = (const float*)d_in[6];
    const float* W2 = (const float*)d_in[7];  const float* B2 = (const float*)d_in[8];
    const float* W3 = (const float*)d_in[9];  const float* B3 = (const float*)d_in[10];

    float* out   = (float*)d_out;
    float* Etot  = out;                    // [B,1]
    float* Ei    = out + Bn;               // [B,N,1]
    float* Force = out + Bn + Bn * Nn;     // [B,N,3]

    float* featp   = (float*)d_ws;                               // NATOMS*64 f32
    float* partial = featp + (size_t)NATOMS * 64;                // 132*3075 f32
    int*   order   = (int*)(partial + (size_t)MF_BLOCKS * PSTRIDE);
    unsigned short* wsu = (unsigned short*)(order + Bn * OBATCH);

    stage1_kernel  <<<PREP_BLKS + NATOMS, 256, 0, stream>>>(itype, nlist, dR,
                                                            W0, W1, W2,
                                                            order, wsu, featp, Etot);
    mlpforce_kernel<<<MF_BLOCKS, 512, 0, stream>>>(featp, itype, nlist, dR,
                                                   order, wsu,
                                                   B0, B1, B2, W3, B3,
                                                   Ei, Etot, partial);
    freduce_kernel <<<(Bn * Nn * 3 + 255) / 256, 256, 0, stream>>>(partial, Force);
}